// Round 4
// baseline (1537.299 us; speedup 1.0000x reference)
//
#include <hip/hip_runtime.h>

typedef __attribute__((ext_vector_type(8))) short short8;
typedef __attribute__((ext_vector_type(4))) float f32x4;

#define ACT_ELEMS 22347776ul   /* 4 * 21824 * 256 */
#define WSTEP     589824       /* 9 * 32 * 256 * 8 */

__device__ unsigned short g_actC[ACT_ELEMS];
__device__ unsigned short g_actA0[ACT_ELEMS];
__device__ unsigned short g_actB0[ACT_ELEMS];
__device__ unsigned short g_actA1[ACT_ELEMS];
__device__ unsigned short g_actB1[ACT_ELEMS];
__device__ unsigned short g_wc[4 * WSTEP];
__device__ unsigned short g_wr[4 * WSTEP];
__device__ unsigned short g_w1c[80 * 256];

__constant__ int      C_W[5]    = {128, 64, 32, 16, 8};
__constant__ int      C_LXT[5]  = {4, 3, 2, 1, 0};          // log2(x-tiles)
__constant__ int      C_PREF2[5]= {0, 256, 320, 336, 340};  // prefix of tiles*2cohalves
__constant__ int      C_HW[5]   = {16384, 4096, 1024, 256, 64};
__constant__ unsigned C_LOFF[5] = {0u, 16777216u, 20971520u, 22020096u, 22282240u};
__constant__ unsigned C_CLSO[5] = {0u, 5242880u, 6553600u, 6881280u, 6963200u};
__constant__ unsigned C_REGO[5] = {6983680u, 7245824u, 7311360u, 7327744u, 7331840u};
__constant__ unsigned C_CENTO[5]= {7332864u, 7398400u, 7414784u, 7418880u, 7419904u};
__constant__ float    C_STRF[5] = {8.f, 16.f, 32.f, 64.f, 128.f};

static __device__ __forceinline__ unsigned short f2bf(float f) {
    unsigned u = __float_as_uint(f);
    unsigned r = (u + 0x7FFFu + ((u >> 16) & 1u)) >> 16;
    return (unsigned short)r;
}
static __device__ __forceinline__ float bf2f(unsigned short b) {
    return __uint_as_float(((unsigned)b) << 16);
}

// ---------------------------------------------------------------------------
// weight convert: (4,256,256,3,3) fp32 -> [step*9+tap][ci/8][co][ci%8] bf16
// grid: (256 co, 36 step*tap, 2 head), block 256 = ci
// ---------------------------------------------------------------------------
__global__ __launch_bounds__(256) void cvt_w3(
    const float* __restrict__ wc, const float* __restrict__ wr,
    unsigned short* __restrict__ oc, unsigned short* __restrict__ orr)
{
    const int co = blockIdx.x, sm = blockIdx.y, head = blockIdx.z;
    const int step = sm / 9, tap = sm - step * 9;
    const int ci = threadIdx.x;
    const float* w = head ? wr : wc;
    unsigned short* o = head ? orr : oc;
    o[(((size_t)sm * 32 + (ci >> 3)) * 256 + co) * 8 + (ci & 7)] =
        f2bf(w[(((size_t)step * 256 + co) * 256 + ci) * 9 + tap]);
}

// 1x1 cls weight convert: (80,256) fp32 -> bf16
__global__ __launch_bounds__(256) void cvt_w1(
    const float* __restrict__ w, unsigned short* __restrict__ o)
{
    for (int idx = threadIdx.x; idx < 80 * 256; idx += 256)
        o[idx] = f2bf(w[idx]);
}

// ---------------------------------------------------------------------------
// input convert: fp32 NCHW -> bf16 NHWC.  grid: (256 px-tiles, 5 lvl, 4 n)
// ---------------------------------------------------------------------------
__global__ __launch_bounds__(256) void cvt_in(
    const float* __restrict__ f0, const float* __restrict__ f1,
    const float* __restrict__ f2, const float* __restrict__ f3,
    const float* __restrict__ f4, unsigned short* __restrict__ dstC)
{
    const int lvl = blockIdx.y, n = blockIdx.z;
    const int HW = C_HW[lvl];
    const int p0 = blockIdx.x * 64;
    if (p0 >= HW) return;
    const float* fp[5] = {f0, f1, f2, f3, f4};
    const float* src = fp[lvl] + (size_t)n * 256 * HW;
    unsigned short* dst = dstC + C_LOFF[lvl] + (size_t)n * HW * 256;
    const int tid = threadIdx.x;
    __shared__ float ts[64][65];

    for (int cc = 0; cc < 256; cc += 64) {
        for (int idx = tid; idx < 64 * 64; idx += 256) {
            int ci = idx >> 6, p = idx & 63;
            ts[ci][p] = src[(size_t)(cc + ci) * HW + p0 + p];
        }
        __syncthreads();
        for (int idx = tid; idx < 64 * 64; idx += 256) {
            int p = idx >> 6, ci = idx & 63;
            dst[(size_t)(p0 + p) * 256 + cc + ci] = f2bf(ts[ci][p]);
        }
        __syncthreads();
    }
}

// ---------------------------------------------------------------------------
// 3x3 conv + BN + ReLU, bf16 MFMA implicit GEMM, y-as-lane B layout,
// register-prefetch software pipeline on the staging loads.
// grid: (342 packed tile*cohalf, 1, 8 = head*4+n), block 256 = 4 waves.
// Block tile: 128 co x (16y x 8x) px.  Wave: 64 co x (16y x 4x) px.
// ---------------------------------------------------------------------------
__global__ __launch_bounds__(256, 4) void conv3x3_mfma(
    const unsigned short* __restrict__ src0, const unsigned short* __restrict__ src1,
    unsigned short* __restrict__ dst0, unsigned short* __restrict__ dst1,
    const unsigned short* __restrict__ wt0, const unsigned short* __restrict__ wt1,
    const float* __restrict__ sc0, const float* __restrict__ bi0,
    const float* __restrict__ sc1, const float* __restrict__ bi1)
{
    int tc = blockIdx.x;
    const int lvl = (tc >= 256) + (tc >= 320) + (tc >= 336) + (tc >= 340);
    tc -= C_PREF2[lvl];
    const int head = blockIdx.z >> 2, n = blockIdx.z & 3;

    const int W = C_W[lvl], H = W;
    const int lxt = C_LXT[lvl];
    const int coh = tc & 1, tile = tc >> 1;
    const int tx = tile & ((1 << lxt) - 1), ty = tile >> lxt;
    const int x0 = tx * 8, y0 = ty * 16;

    const unsigned short* src = head ? src1 : src0;
    unsigned short*       dst = head ? dst1 : dst0;
    const unsigned short* wt  = head ? wt1 : wt0;
    const float* sc = head ? sc1 : sc0;
    const float* bi = head ? bi1 : bi0;
    const size_t actOff = (size_t)C_LOFF[lvl] + (size_t)n * ((size_t)H * W) * 256;
    src += actOff; dst += actOff;

    const int tid = threadIdx.x;
    const int lane = tid & 63, wid = tid >> 6;
    const int l16 = lane & 15, quad = lane >> 4;
    const int mh = wid & 1, wn = wid >> 1;

    const int cow = coh * 128 + mh * 64;   // wave co base
    const int x0w = x0 + wn * 4;           // wave x base (global)
    const int jw  = wn * 4;                // wave x base (LDS-local)

    // LDS: [g(8)][x(10, stride 11)][y(18)] x 8ci x 2B = 25344 B
    __shared__ unsigned short bsh[8 * 11 * 18 * 8];
    char* bb = (char*)bsh;

    // ---- per-thread staging slots (6 x uint4), addresses precomputed ----
    int goff[6], pfa[6];
#pragma unroll
    for (int it = 0; it < 6; it++) {
        int idx = tid + it * 256;
        int g = idx & 7, pos = idx >> 3;
        int y = (pos * 205) >> 11;        // /10
        int x = pos - y * 10;
        int gy = y0 + y - 1, gx = x0 + x - 1;
        bool ok = (idx < 1440) && ((unsigned)gy < (unsigned)H) && ((unsigned)gx < (unsigned)W);
        goff[it] = ok ? (((gy * W + gx) << 8) + g * 8) : -1;
        pfa[it]  = ((g * 11 + x) * 18 + y) * 16;
    }
    const bool w5 = tid < 160;   // it=5 valid slots (1440 - 1280)

    f32x4 acc[4][4];
#pragma unroll
    for (int mf = 0; mf < 4; mf++)
#pragma unroll
        for (int nf = 0; nf < 4; nf++) acc[mf][nf] = (f32x4){0.f, 0.f, 0.f, 0.f};

    const int ldsRB = (quad * 198 + l16) * 16;          // 198 = 11*18
    const char* aB  = (const char*)wt + (quad * 256 + l16) * 16;

    // ---- prologue: prefetch chunk 0 ----
    uint4 pf[6];
#pragma unroll
    for (int it = 0; it < 6; it++) {
        uint4 v; v.x = v.y = v.z = v.w = 0u;
        if (goff[it] >= 0) v = *(const uint4*)(src + goff[it]);
        pf[it] = v;
    }

    for (int cc = 0; cc < 256; cc += 64) {
        __syncthreads();
        // ---- write staged regs to LDS ----
#pragma unroll
        for (int it = 0; it < 5; it++) *(uint4*)(bb + pfa[it]) = pf[it];
        if (w5) *(uint4*)(bb + pfa[5]) = pf[5];
        // ---- issue next chunk's loads (fly during MFMA below) ----
        if (cc < 192) {
#pragma unroll
            for (int it = 0; it < 6; it++) {
                uint4 v; v.x = v.y = v.z = v.w = 0u;
                if (goff[it] >= 0) v = *(const uint4*)(src + goff[it] + cc + 64);
                pf[it] = v;
            }
        }
        __syncthreads();

        const int cc8 = cc >> 3;
#pragma unroll
        for (int kk = 0; kk < 2; kk++) {
#pragma unroll
            for (int kh = 0; kh < 3; kh++) {
                short8 Bf[6];
#pragma unroll
                for (int j = 0; j < 6; j++)
                    Bf[j] = *(const short8*)(bb + ldsRB +
                                (kk * 792 + (jw + j) * 18 + kh) * 16);
#pragma unroll
                for (int kw = 0; kw < 3; kw++) {
                    const int tap = kh * 3 + kw;
                    short8 Af[4];
#pragma unroll
                    for (int mf = 0; mf < 4; mf++)
                        Af[mf] = *(const short8*)(aB +
                            (((tap * 32 + cc8 + kk * 4) * 256) + cow + mf * 16) * 16);
#pragma unroll
                    for (int nf = 0; nf < 4; nf++)
#pragma unroll
                        for (int mf = 0; mf < 4; mf++)
                            acc[mf][nf] = __builtin_amdgcn_mfma_f32_16x16x32_bf16(
                                Af[mf], Bf[nf + kw], acc[mf][nf], 0, 0, 0);
                }
            }
        }
    }

    // ---- epilogue: BN + ReLU + cvt bf16, NHWC store ----
    const int gy = y0 + l16;
    if (gy < H) {
#pragma unroll
        for (int mf = 0; mf < 4; mf++) {
            const int co4 = cow + mf * 16 + quad * 4;
            const f32x4 s4 = *(const f32x4*)(sc + co4);
            const f32x4 b4 = *(const f32x4*)(bi + co4);
#pragma unroll
            for (int nf = 0; nf < 4; nf++) {
                const int gx = x0w + nf;
                f32x4 v = acc[mf][nf];
                ushort4 o;
                o.x = f2bf(fmaxf(v[0] * s4[0] + b4[0], 0.f));
                o.y = f2bf(fmaxf(v[1] * s4[1] + b4[1], 0.f));
                o.z = f2bf(fmaxf(v[2] * s4[2] + b4[2], 0.f));
                o.w = f2bf(fmaxf(v[3] * s4[3] + b4[3], 0.f));
                *(ushort4*)(dst + ((gy * W + gx) * 256 + co4)) = o;
            }
        }
    }
}

// ---------------------------------------------------------------------------
// final 1x1 cls: 256 -> 80 + bias, MFMA, fp32 NCHW out.
// grid: (128 px-tiles, 5 lvl, 4 n), block 256 = 4 waves; wave: 80co x 32px.
// ---------------------------------------------------------------------------
__global__ __launch_bounds__(256) void final_cls(
    const unsigned short* __restrict__ act, const unsigned short* __restrict__ w,
    const float* __restrict__ bias, float* __restrict__ out)
{
    const int lvl = blockIdx.y, n = blockIdx.z;
    const int HW = C_HW[lvl];
    const int p0 = blockIdx.x * 128;
    if (p0 >= HW) return;

    const int tid = threadIdx.x;
    const int lane = tid & 63, wid = tid >> 6;
    const int l16 = lane & 15, quad = lane >> 4;

    const unsigned short* a = act + C_LOFF[lvl] + (size_t)n * HW * 256;

    int px[2], lpx[2];
#pragma unroll
    for (int j = 0; j < 2; j++) {
        px[j] = p0 + wid * 32 + j * 16 + l16;
        lpx[j] = px[j] < HW ? px[j] : 0;
    }

    f32x4 acc[5][2];
#pragma unroll
    for (int mf = 0; mf < 5; mf++) { acc[mf][0] = (f32x4){0,0,0,0}; acc[mf][1] = (f32x4){0,0,0,0}; }

    for (int cc = 0; cc < 256; cc += 32) {
        short8 b0 = *(const short8*)(a + (size_t)lpx[0] * 256 + cc + quad * 8);
        short8 b1 = *(const short8*)(a + (size_t)lpx[1] * 256 + cc + quad * 8);
#pragma unroll
        for (int mf = 0; mf < 5; mf++) {
            short8 av = *(const short8*)(w + (mf * 16 + l16) * 256 + cc + quad * 8);
            acc[mf][0] = __builtin_amdgcn_mfma_f32_16x16x32_bf16(av, b0, acc[mf][0], 0, 0, 0);
            acc[mf][1] = __builtin_amdgcn_mfma_f32_16x16x32_bf16(av, b1, acc[mf][1], 0, 0, 0);
        }
    }

    float* ob = out + C_CLSO[lvl] + (size_t)n * 80 * HW;
#pragma unroll
    for (int mf = 0; mf < 5; mf++) {
        const int co0 = mf * 16 + quad * 4;
#pragma unroll
        for (int j = 0; j < 2; j++) {
            if (px[j] < HW) {
#pragma unroll
                for (int r = 0; r < 4; r++)
                    ob[(size_t)(co0 + r) * HW + px[j]] = acc[mf][j][r] + bias[co0 + r];
            }
        }
    }
}

// ---------------------------------------------------------------------------
// final 1x1 reg: 256 -> 5 + bias; ch0 centerness, ch1..4 max(raw*stride,0).
// ---------------------------------------------------------------------------
__global__ __launch_bounds__(256) void final_reg(
    const unsigned short* __restrict__ act, const float* __restrict__ w,
    const float* __restrict__ bias, float* __restrict__ out)
{
    const int lvl = blockIdx.y, n = blockIdx.z;
    const int HW = C_HW[lvl];
    const int tid = threadIdx.x;

    __shared__ float ws[5 * 256];
    for (int idx = tid; idx < 5 * 256; idx += 256) ws[idx] = w[idx];
    __syncthreads();

    const int px = blockIdx.x * 256 + tid;
    if (px >= HW) return;

    const unsigned short* a = act + C_LOFF[lvl] + ((size_t)n * HW + px) * 256;
    float acc[5] = {0.f, 0.f, 0.f, 0.f, 0.f};

    for (int ci = 0; ci < 256; ci += 8) {
        ushort4 u0 = *(const ushort4*)(a + ci);
        ushort4 u1 = *(const ushort4*)(a + ci + 4);
        float xv[8] = {bf2f(u0.x), bf2f(u0.y), bf2f(u0.z), bf2f(u0.w),
                       bf2f(u1.x), bf2f(u1.y), bf2f(u1.z), bf2f(u1.w)};
#pragma unroll
        for (int j = 0; j < 5; j++) {
            const float* wj = &ws[j * 256 + ci];
#pragma unroll
            for (int k = 0; k < 8; k++) acc[j] = fmaf(xv[k], wj[k], acc[j]);
        }
    }

    const float strf = C_STRF[lvl];
    out[C_CENTO[lvl] + (size_t)n * HW + px] = acc[0] + bias[0];
    float* rb = out + C_REGO[lvl] + (size_t)n * 4 * HW;
#pragma unroll
    for (int j = 0; j < 4; j++)
        rb[(size_t)j * HW + px] = fmaxf((acc[j + 1] + bias[j + 1]) * strf, 0.f);
}

// ---------------------------------------------------------------------------
extern "C" void kernel_launch(void* const* d_in, const int* in_sizes, int n_in,
                              void* d_out, int out_size, void* d_ws, size_t ws_size,
                              hipStream_t stream)
{
    const float* cls_w  = (const float*)d_in[5];
    const float* cls_s  = (const float*)d_in[6];
    const float* cls_b  = (const float*)d_in[7];
    const float* cls_fw = (const float*)d_in[8];
    const float* cls_fb = (const float*)d_in[9];
    const float* reg_w  = (const float*)d_in[10];
    const float* reg_s  = (const float*)d_in[11];
    const float* reg_b  = (const float*)d_in[12];
    const float* reg_fw = (const float*)d_in[13];
    const float* reg_fb = (const float*)d_in[14];
    float* out = (float*)d_out;

    unsigned short *actC, *actA0, *actB0, *actA1, *actB1, *wc, *wr, *w1c;
    hipGetSymbolAddress((void**)&actC,  HIP_SYMBOL(g_actC));
    hipGetSymbolAddress((void**)&actA0, HIP_SYMBOL(g_actA0));
    hipGetSymbolAddress((void**)&actB0, HIP_SYMBOL(g_actB0));
    hipGetSymbolAddress((void**)&actA1, HIP_SYMBOL(g_actA1));
    hipGetSymbolAddress((void**)&actB1, HIP_SYMBOL(g_actB1));
    hipGetSymbolAddress((void**)&wc,    HIP_SYMBOL(g_wc));
    hipGetSymbolAddress((void**)&wr,    HIP_SYMBOL(g_wr));
    hipGetSymbolAddress((void**)&w1c,   HIP_SYMBOL(g_w1c));

    // weight + input conversion
    cvt_w3<<<dim3(256, 36, 2), 256, 0, stream>>>(cls_w, reg_w, wc, wr);
    cvt_w1<<<1, 256, 0, stream>>>(cls_fw, w1c);
    cvt_in<<<dim3(256, 5, 4), 256, 0, stream>>>(
        (const float*)d_in[0], (const float*)d_in[1], (const float*)d_in[2],
        (const float*)d_in[3], (const float*)d_in[4], actC);

    // 4 conv steps, both heads + all levels + all n batched per launch
    unsigned short* srcs[4][2] = {{actC, actC}, {actA0, actA1}, {actB0, actB1}, {actA0, actA1}};
    unsigned short* dsts[4][2] = {{actA0, actA1}, {actB0, actB1}, {actA0, actA1}, {actB0, actB1}};
    for (int s = 0; s < 4; s++) {
        conv3x3_mfma<<<dim3(342, 1, 8), 256, 0, stream>>>(
            srcs[s][0], srcs[s][1], dsts[s][0], dsts[s][1],
            wc + (size_t)s * WSTEP, wr + (size_t)s * WSTEP,
            cls_s + s * 256, cls_b + s * 256, reg_s + s * 256, reg_b + s * 256);
    }

    // finals
    final_cls<<<dim3(128, 5, 4), 256, 0, stream>>>(actB0, w1c, cls_fb, out);
    final_reg<<<dim3(64, 5, 4), 256, 0, stream>>>(actB1, reg_fw, reg_fb, out);
}

// Round 5
// 1344.230 us; speedup vs baseline: 1.1436x; 1.1436x over previous
//
#include <hip/hip_runtime.h>

typedef __attribute__((ext_vector_type(8))) short short8;
typedef __attribute__((ext_vector_type(4))) float f32x4;

#define ACT_P 23384064ul       /* padded: sum(HpWp)*256*4n */
#define WSTEP 589824           /* 9 * 32 * 256 * 8 */

__device__ unsigned short g_actC[ACT_P];
__device__ unsigned short g_actA0[ACT_P];
__device__ unsigned short g_actB0[ACT_P];
__device__ unsigned short g_actA1[ACT_P];
__device__ unsigned short g_actB1[ACT_P];
__device__ unsigned short g_wc[4 * WSTEP];
__device__ unsigned short g_wr[4 * WSTEP];
__device__ unsigned short g_w1c[80 * 256];

__constant__ int      C_W[5]    = {128, 64, 32, 16, 8};
__constant__ int      C_WP[5]   = {130, 66, 34, 18, 10};
__constant__ int      C_HWP[5]  = {16900, 4356, 1156, 324, 100};
__constant__ int      C_LW[5]   = {7, 6, 5, 4, 3};
__constant__ int      C_LXT[5]  = {4, 3, 2, 1, 0};
__constant__ int      C_PREF2[5]= {0, 256, 320, 336, 340};
__constant__ int      C_HW[5]   = {16384, 4096, 1024, 256, 64};
__constant__ unsigned C_LOFFP[5]= {0u, 17305600u, 21766144u, 22949888u, 23281664u};
__constant__ unsigned C_CLSO[5] = {0u, 5242880u, 6553600u, 6881280u, 6963200u};
__constant__ unsigned C_REGO[5] = {6983680u, 7245824u, 7311360u, 7327744u, 7331840u};
__constant__ unsigned C_CENTO[5]= {7332864u, 7398400u, 7414784u, 7418880u, 7419904u};
__constant__ float    C_STRF[5] = {8.f, 16.f, 32.f, 64.f, 128.f};

static __device__ __forceinline__ unsigned short f2bf(float f) {
    unsigned u = __float_as_uint(f);
    unsigned r = (u + 0x7FFFu + ((u >> 16) & 1u)) >> 16;
    return (unsigned short)r;
}
static __device__ __forceinline__ float bf2f(unsigned short b) {
    return __uint_as_float(((unsigned)b) << 16);
}

// ---------------------------------------------------------------------------
// weight convert: (4,256,256,3,3) fp32 -> [step*9+tap][ci/8][co][ci%8] bf16
// ---------------------------------------------------------------------------
__global__ __launch_bounds__(256) void cvt_w3(
    const float* __restrict__ wc, const float* __restrict__ wr,
    unsigned short* __restrict__ oc, unsigned short* __restrict__ orr)
{
    const int co = blockIdx.x, sm = blockIdx.y, head = blockIdx.z;
    const int step = sm / 9, tap = sm - step * 9;
    const int ci = threadIdx.x;
    const float* w = head ? wr : wc;
    unsigned short* o = head ? orr : oc;
    o[(((size_t)sm * 32 + (ci >> 3)) * 256 + co) * 8 + (ci & 7)] =
        f2bf(w[(((size_t)step * 256 + co) * 256 + ci) * 9 + tap]);
}

__global__ __launch_bounds__(256) void cvt_w1(
    const float* __restrict__ w, unsigned short* __restrict__ o)
{
    for (int idx = threadIdx.x; idx < 80 * 256; idx += 256)
        o[idx] = f2bf(w[idx]);
}

// ---------------------------------------------------------------------------
// zero the 1-px halo border of every level/n of all 5 padded buffers
// grid: 100 blocks = buf(5) x lvl(5) x n(4)
// ---------------------------------------------------------------------------
__global__ __launch_bounds__(256) void zero_halo(
    unsigned short* c, unsigned short* a0, unsigned short* b0,
    unsigned short* a1, unsigned short* b1)
{
    unsigned short* bufs[5] = {c, a0, b0, a1, b1};
    const int bid = blockIdx.x;
    const int buf = bid / 20, r = bid - buf * 20, lvl = r >> 2, n = r & 3;
    const int Wp = C_WP[lvl], Hp = Wp;
    unsigned short* base = bufs[buf] + C_LOFFP[lvl] + (size_t)n * C_HWP[lvl] * 256;
    const int hc = 2 * Wp + 2 * (Hp - 2);
    uint4 z; z.x = z.y = z.z = z.w = 0u;
    for (int idx = threadIdx.x; idx < hc * 32; idx += 256) {
        int pos = idx >> 5, q = idx & 31;
        int row, col;
        if (pos < 2 * Wp) { row = (pos >= Wp) ? (Hp - 1) : 0; col = (pos >= Wp) ? pos - Wp : pos; }
        else { int rem = pos - 2 * Wp; row = 1 + (rem >> 1); col = (rem & 1) ? (Wp - 1) : 0; }
        *(uint4*)(base + ((size_t)(row * Wp + col) << 8) + q * 8) = z;
    }
}

// ---------------------------------------------------------------------------
// input convert: fp32 NCHW -> bf16 padded NHWC.  grid: (256 px-tiles, 5 lvl, 4 n)
// ---------------------------------------------------------------------------
__global__ __launch_bounds__(256) void cvt_in(
    const float* __restrict__ f0, const float* __restrict__ f1,
    const float* __restrict__ f2, const float* __restrict__ f3,
    const float* __restrict__ f4, unsigned short* __restrict__ dstC)
{
    const int lvl = blockIdx.y, n = blockIdx.z;
    const int HW = C_HW[lvl];
    const int p0 = blockIdx.x * 64;
    if (p0 >= HW) return;
    const int W = C_W[lvl], lw = C_LW[lvl], Wp = C_WP[lvl];
    const float* fp[5] = {f0, f1, f2, f3, f4};
    const float* src = fp[lvl] + (size_t)n * 256 * HW;
    unsigned short* dst = dstC + C_LOFFP[lvl] + (size_t)n * C_HWP[lvl] * 256;
    const int tid = threadIdx.x;
    __shared__ float ts[64][65];

    for (int cc = 0; cc < 256; cc += 64) {
        for (int idx = tid; idx < 64 * 64; idx += 256) {
            int ci = idx >> 6, p = idx & 63;
            ts[ci][p] = src[(size_t)(cc + ci) * HW + p0 + p];
        }
        __syncthreads();
        for (int idx = tid; idx < 64 * 64; idx += 256) {
            int p = idx >> 6, ci = idx & 63;
            int gp = p0 + p, y = gp >> lw, x = gp & (W - 1);
            dst[(size_t)((y + 1) * Wp + x + 1) * 256 + cc + ci] = f2bf(ts[ci][p]);
        }
        __syncthreads();
    }
}

// ---------------------------------------------------------------------------
// 3x3 conv + BN + ReLU, bf16 MFMA implicit GEMM, y-as-lane B layout,
// register-prefetch pipeline, padded buffers (no bounds checks).
// grid: (342 packed tile*cohalf, 1, 8 = head*4+n), block 256 = 4 waves.
// ---------------------------------------------------------------------------
__global__ __launch_bounds__(256, 3) void conv3x3_mfma(
    const unsigned short* __restrict__ src0, const unsigned short* __restrict__ src1,
    unsigned short* __restrict__ dst0, unsigned short* __restrict__ dst1,
    const unsigned short* __restrict__ wt0, const unsigned short* __restrict__ wt1,
    const float* __restrict__ sc0, const float* __restrict__ bi0,
    const float* __restrict__ sc1, const float* __restrict__ bi1)
{
    int tc = blockIdx.x;
    const int lvl = (tc >= 256) + (tc >= 320) + (tc >= 336) + (tc >= 340);
    tc -= C_PREF2[lvl];
    const int head = blockIdx.z >> 2, n = blockIdx.z & 3;

    const int W = C_W[lvl], H = W, Wp = C_WP[lvl];
    const int lxt = C_LXT[lvl];
    const int coh = tc & 1, tile = tc >> 1;
    const int tx = tile & ((1 << lxt) - 1), ty = tile >> lxt;
    const int x0 = tx * 8, y0 = ty * 16;

    const unsigned short* src = head ? src1 : src0;
    unsigned short*       dst = head ? dst1 : dst0;
    const unsigned short* wt  = head ? wt1 : wt0;
    const float* sc = head ? sc1 : sc0;
    const float* bi = head ? bi1 : bi0;
    const size_t actOff = (size_t)C_LOFFP[lvl] + (size_t)n * C_HWP[lvl] * 256;
    src += actOff; dst += actOff;

    const int tid = threadIdx.x;
    const int lane = tid & 63, wid = tid >> 6;
    const int l16 = lane & 15, quad = lane >> 4;
    const int mh = wid & 1, wn = wid >> 1;

    const int cow = coh * 128 + mh * 64;
    const int x0w = x0 + wn * 4;
    const int jw  = wn * 4;

    // LDS: [g(8)][x(10, stride 11)][y(18)] x 8ci x 2B = 25344 B
    __shared__ unsigned short bsh[8 * 11 * 18 * 8];
    char* bb = (char*)bsh;

    // ---- per-thread staging slots (6 x uint4); padded layout -> no masks ----
    int goff[6], pfa[6];
#pragma unroll
    for (int it = 0; it < 6; it++) {
        int idx = tid + it * 256;
        if (idx > 1439) idx = 1439;          // benign duplicate for tail slots
        int g = idx & 7, pos = idx >> 3;
        int y = (pos * 205) >> 11;           // /10
        int x = pos - y * 10;
        int gyp = y0 + y;                    // padded row; clamp (lvl4) onto zero halo row
        if (gyp > Wp - 1) gyp = Wp - 1;
        goff[it] = ((gyp * Wp + x0 + x) << 8) + g * 8;
        pfa[it]  = ((g * 11 + x) * 18 + y) * 16;
    }

    f32x4 acc[4][4];
#pragma unroll
    for (int mf = 0; mf < 4; mf++)
#pragma unroll
        for (int nf = 0; nf < 4; nf++) acc[mf][nf] = (f32x4){0.f, 0.f, 0.f, 0.f};

    const int ldsRB = (quad * 198 + l16) * 16;          // 198 = 11*18
    const char* aB  = (const char*)wt + (quad * 256 + l16) * 16;

    // ---- prologue: prefetch chunk 0 ----
    uint4 pf[6];
#pragma unroll
    for (int it = 0; it < 6; it++) pf[it] = *(const uint4*)(src + goff[it]);

    for (int cc = 0; cc < 256; cc += 64) {
        __syncthreads();
#pragma unroll
        for (int it = 0; it < 6; it++) *(uint4*)(bb + pfa[it]) = pf[it];
        if (cc < 192) {
#pragma unroll
            for (int it = 0; it < 6; it++)
                pf[it] = *(const uint4*)(src + goff[it] + cc + 64);
        }
        __syncthreads();

        const int cc8 = cc >> 3;
#pragma unroll
        for (int kk = 0; kk < 2; kk++) {
#pragma unroll
            for (int kh = 0; kh < 3; kh++) {
                short8 Bf[6];
#pragma unroll
                for (int j = 0; j < 6; j++)
                    Bf[j] = *(const short8*)(bb + ldsRB +
                                (kk * 792 + (jw + j) * 18 + kh) * 16);
#pragma unroll
                for (int kw = 0; kw < 3; kw++) {
                    const int tap = kh * 3 + kw;
                    short8 Af[4];
#pragma unroll
                    for (int mf = 0; mf < 4; mf++)
                        Af[mf] = *(const short8*)(aB +
                            (((tap * 32 + cc8 + kk * 4) * 256) + cow + mf * 16) * 16);
#pragma unroll
                    for (int nf = 0; nf < 4; nf++)
#pragma unroll
                        for (int mf = 0; mf < 4; mf++)
                            acc[mf][nf] = __builtin_amdgcn_mfma_f32_16x16x32_bf16(
                                Af[mf], Bf[nf + kw], acc[mf][nf], 0, 0, 0);
                }
            }
        }
    }

    // ---- epilogue: BN + ReLU + cvt bf16, padded NHWC store ----
    const int gy = y0 + l16;
    if (gy < H) {
#pragma unroll
        for (int mf = 0; mf < 4; mf++) {
            const int co4 = cow + mf * 16 + quad * 4;
            const f32x4 s4 = *(const f32x4*)(sc + co4);
            const f32x4 b4 = *(const f32x4*)(bi + co4);
#pragma unroll
            for (int nf = 0; nf < 4; nf++) {
                const int gx = x0w + nf;
                f32x4 v = acc[mf][nf];
                ushort4 o;
                o.x = f2bf(fmaxf(v[0] * s4[0] + b4[0], 0.f));
                o.y = f2bf(fmaxf(v[1] * s4[1] + b4[1], 0.f));
                o.z = f2bf(fmaxf(v[2] * s4[2] + b4[2], 0.f));
                o.w = f2bf(fmaxf(v[3] * s4[3] + b4[3], 0.f));
                *(ushort4*)(dst + ((size_t)((gy + 1) * Wp + gx + 1) * 256 + co4)) = o;
            }
        }
    }
}

// ---------------------------------------------------------------------------
// final 1x1 cls: 256 -> 80 + bias, MFMA, fp32 NCHW out (padded NHWC input).
// grid: (128 px-tiles, 5 lvl, 4 n), block 256 = 4 waves; wave: 80co x 32px.
// ---------------------------------------------------------------------------
__global__ __launch_bounds__(256) void final_cls(
    const unsigned short* __restrict__ act, const unsigned short* __restrict__ w,
    const float* __restrict__ bias, float* __restrict__ out)
{
    const int lvl = blockIdx.y, n = blockIdx.z;
    const int HW = C_HW[lvl];
    const int p0 = blockIdx.x * 128;
    if (p0 >= HW) return;
    const int W = C_W[lvl], lw = C_LW[lvl], Wp = C_WP[lvl];

    const int tid = threadIdx.x;
    const int lane = tid & 63, wid = tid >> 6;
    const int l16 = lane & 15, quad = lane >> 4;

    const unsigned short* a = act + C_LOFFP[lvl] + (size_t)n * C_HWP[lvl] * 256;

    int px[2]; size_t aoff[2];
#pragma unroll
    for (int j = 0; j < 2; j++) {
        px[j] = p0 + wid * 32 + j * 16 + l16;
        int lpx = px[j] < HW ? px[j] : 0;
        int y = lpx >> lw, x = lpx & (W - 1);
        aoff[j] = (size_t)((y + 1) * Wp + x + 1) * 256;
    }

    f32x4 acc[5][2];
#pragma unroll
    for (int mf = 0; mf < 5; mf++) { acc[mf][0] = (f32x4){0,0,0,0}; acc[mf][1] = (f32x4){0,0,0,0}; }

    for (int cc = 0; cc < 256; cc += 32) {
        short8 b0 = *(const short8*)(a + aoff[0] + cc + quad * 8);
        short8 b1 = *(const short8*)(a + aoff[1] + cc + quad * 8);
#pragma unroll
        for (int mf = 0; mf < 5; mf++) {
            short8 av = *(const short8*)(w + (mf * 16 + l16) * 256 + cc + quad * 8);
            acc[mf][0] = __builtin_amdgcn_mfma_f32_16x16x32_bf16(av, b0, acc[mf][0], 0, 0, 0);
            acc[mf][1] = __builtin_amdgcn_mfma_f32_16x16x32_bf16(av, b1, acc[mf][1], 0, 0, 0);
        }
    }

    float* ob = out + C_CLSO[lvl] + (size_t)n * 80 * HW;
#pragma unroll
    for (int mf = 0; mf < 5; mf++) {
        const int co0 = mf * 16 + quad * 4;
#pragma unroll
        for (int j = 0; j < 2; j++) {
            if (px[j] < HW) {
#pragma unroll
                for (int r = 0; r < 4; r++)
                    ob[(size_t)(co0 + r) * HW + px[j]] = acc[mf][j][r] + bias[co0 + r];
            }
        }
    }
}

// ---------------------------------------------------------------------------
// final 1x1 reg: 256 -> 5 + bias; ch0 centerness, ch1..4 max(raw*stride,0).
// ---------------------------------------------------------------------------
__global__ __launch_bounds__(256) void final_reg(
    const unsigned short* __restrict__ act, const float* __restrict__ w,
    const float* __restrict__ bias, float* __restrict__ out)
{
    const int lvl = blockIdx.y, n = blockIdx.z;
    const int HW = C_HW[lvl];
    const int W = C_W[lvl], lw = C_LW[lvl], Wp = C_WP[lvl];
    const int tid = threadIdx.x;

    __shared__ float ws[5 * 256];
    for (int idx = tid; idx < 5 * 256; idx += 256) ws[idx] = w[idx];
    __syncthreads();

    const int px = blockIdx.x * 256 + tid;
    if (px >= HW) return;

    const int y = px >> lw, x = px & (W - 1);
    const unsigned short* a = act + C_LOFFP[lvl] + (size_t)n * C_HWP[lvl] * 256
                            + (size_t)((y + 1) * Wp + x + 1) * 256;
    float acc[5] = {0.f, 0.f, 0.f, 0.f, 0.f};

    for (int ci = 0; ci < 256; ci += 8) {
        ushort4 u0 = *(const ushort4*)(a + ci);
        ushort4 u1 = *(const ushort4*)(a + ci + 4);
        float xv[8] = {bf2f(u0.x), bf2f(u0.y), bf2f(u0.z), bf2f(u0.w),
                       bf2f(u1.x), bf2f(u1.y), bf2f(u1.z), bf2f(u1.w)};
#pragma unroll
        for (int j = 0; j < 5; j++) {
            const float* wj = &ws[j * 256 + ci];
#pragma unroll
            for (int k = 0; k < 8; k++) acc[j] = fmaf(xv[k], wj[k], acc[j]);
        }
    }

    const float strf = C_STRF[lvl];
    out[C_CENTO[lvl] + (size_t)n * HW + px] = acc[0] + bias[0];
    float* rb = out + C_REGO[lvl] + (size_t)n * 4 * HW;
#pragma unroll
    for (int j = 0; j < 4; j++)
        rb[(size_t)j * HW + px] = fmaxf((acc[j + 1] + bias[j + 1]) * strf, 0.f);
}

// ---------------------------------------------------------------------------
extern "C" void kernel_launch(void* const* d_in, const int* in_sizes, int n_in,
                              void* d_out, int out_size, void* d_ws, size_t ws_size,
                              hipStream_t stream)
{
    const float* cls_w  = (const float*)d_in[5];
    const float* cls_s  = (const float*)d_in[6];
    const float* cls_b  = (const float*)d_in[7];
    const float* cls_fw = (const float*)d_in[8];
    const float* cls_fb = (const float*)d_in[9];
    const float* reg_w  = (const float*)d_in[10];
    const float* reg_s  = (const float*)d_in[11];
    const float* reg_b  = (const float*)d_in[12];
    const float* reg_fw = (const float*)d_in[13];
    const float* reg_fb = (const float*)d_in[14];
    float* out = (float*)d_out;

    unsigned short *actC, *actA0, *actB0, *actA1, *actB1, *wc, *wr, *w1c;
    hipGetSymbolAddress((void**)&actC,  HIP_SYMBOL(g_actC));
    hipGetSymbolAddress((void**)&actA0, HIP_SYMBOL(g_actA0));
    hipGetSymbolAddress((void**)&actB0, HIP_SYMBOL(g_actB0));
    hipGetSymbolAddress((void**)&actA1, HIP_SYMBOL(g_actA1));
    hipGetSymbolAddress((void**)&actB1, HIP_SYMBOL(g_actB1));
    hipGetSymbolAddress((void**)&wc,    HIP_SYMBOL(g_wc));
    hipGetSymbolAddress((void**)&wr,    HIP_SYMBOL(g_wr));
    hipGetSymbolAddress((void**)&w1c,   HIP_SYMBOL(g_w1c));

    cvt_w3<<<dim3(256, 36, 2), 256, 0, stream>>>(cls_w, reg_w, wc, wr);
    cvt_w1<<<1, 256, 0, stream>>>(cls_fw, w1c);
    zero_halo<<<100, 256, 0, stream>>>(actC, actA0, actB0, actA1, actB1);
    cvt_in<<<dim3(256, 5, 4), 256, 0, stream>>>(
        (const float*)d_in[0], (const float*)d_in[1], (const float*)d_in[2],
        (const float*)d_in[3], (const float*)d_in[4], actC);

    unsigned short* srcs[4][2] = {{actC, actC}, {actA0, actA1}, {actB0, actB1}, {actA0, actA1}};
    unsigned short* dsts[4][2] = {{actA0, actA1}, {actB0, actB1}, {actA0, actA1}, {actB0, actB1}};
    for (int s = 0; s < 4; s++) {
        conv3x3_mfma<<<dim3(342, 1, 8), 256, 0, stream>>>(
            srcs[s][0], srcs[s][1], dsts[s][0], dsts[s][1],
            wc + (size_t)s * WSTEP, wr + (size_t)s * WSTEP,
            cls_s + s * 256, cls_b + s * 256, reg_s + s * 256, reg_b + s * 256);
    }

    final_cls<<<dim3(128, 5, 4), 256, 0, stream>>>(actB0, w1c, cls_fb, out);
    final_reg<<<dim3(64, 5, 4), 256, 0, stream>>>(actB1, reg_fw, reg_fb, out);
}